// Round 1
// 554.055 us; speedup vs baseline: 1.0462x; 1.0462x over previous
//
#include <hip/hip_runtime.h>
#include <hip/hip_bf16.h>
#include <string.h>

typedef __hip_bfloat16  bf16;
typedef __hip_bfloat162 bf162;
typedef __attribute__((ext_vector_type(8))) short short8;
typedef __attribute__((ext_vector_type(4))) float f32x4;

#define NB 16
#define NN 4096
#define NC 512
#define SCALE 0.044194173824159216f  // 1/sqrt(512)

// Direct global->LDS DMA, 16B per lane. LDS dest must be linear in lane order.
#define GLL16(gp, lp) __builtin_amdgcn_global_load_lds( \
    (__attribute__((address_space(1))) void*)(gp),      \
    (__attribute__((address_space(3))) void*)(lp), 16, 0, 0)

// ---------------------------------------------------------------------------
// Kernel 0: cast x [65536,512] fp32 -> bf16 (into d_out region, dead there
// until unspat_kernel overwrites it at the end).
// ---------------------------------------------------------------------------
__global__ __launch_bounds__(256) void cast_x_kernel(
    const float* __restrict__ x, bf16* __restrict__ xb)
{
    size_t i = ((size_t)blockIdx.x * 256 + threadIdx.x) * 8;
    float4 a = *(const float4*)(x + i);
    float4 b = *(const float4*)(x + i + 4);
    bf16 t[8];
    t[0] = __float2bfloat16(a.x); t[1] = __float2bfloat16(a.y);
    t[2] = __float2bfloat16(a.z); t[3] = __float2bfloat16(a.w);
    t[4] = __float2bfloat16(b.x); t[5] = __float2bfloat16(b.y);
    t[6] = __float2bfloat16(b.z); t[7] = __float2bfloat16(b.w);
    uint4 r; memcpy(&r, t, 16);
    *(uint4*)(xb + i) = r;
}

// ---------------------------------------------------------------------------
// Kernel 0b: cast Wq/Wk/Wv [512,512] fp32 -> bf16 ONCE (was re-converted by
// every one of the 512 y-blocks inside proj_mfma's K-loop).
// ---------------------------------------------------------------------------
__global__ __launch_bounds__(256) void cast_w_kernel(
    const float* __restrict__ Wq, const float* __restrict__ Wk,
    const float* __restrict__ Wv, bf16* __restrict__ Wb)
{
    const float* W = (blockIdx.y == 0) ? Wq : (blockIdx.y == 1) ? Wk : Wv;
    size_t i = ((size_t)blockIdx.x * 256 + threadIdx.x) * 8;
    float4 a = *(const float4*)(W + i);
    float4 b = *(const float4*)(W + i + 4);
    bf16 t[8];
    t[0] = __float2bfloat16(a.x); t[1] = __float2bfloat16(a.y);
    t[2] = __float2bfloat16(a.z); t[3] = __float2bfloat16(a.w);
    t[4] = __float2bfloat16(b.x); t[5] = __float2bfloat16(b.y);
    t[6] = __float2bfloat16(b.z); t[7] = __float2bfloat16(b.w);
    uint4 r; memcpy(&r, t, 16);
    *(uint4*)(Wb + (size_t)blockIdx.y * (NC * NC) + i) = r;
}

// ---------------------------------------------------------------------------
// Kernel 1: MFMA projection  y = sigmoid(xb @ W^T + b) -> spatial [B,C,N] bf16.
// m97 structure: 128x128 tile, BK=64, linear LDS, global_load_lds width-16
// staging, 2-barrier K-loop. 4 waves (2x2), 4x4 16x16x32 frags per wave.
// ---------------------------------------------------------------------------
__global__ __launch_bounds__(256) void proj_mfma(
    const bf16* __restrict__ xb, const bf16* __restrict__ Wb,
    const float* __restrict__ bq, const float* __restrict__ bk,
    const float* __restrict__ bv,
    bf16* __restrict__ Qs, bf16* __restrict__ Ks, bf16* __restrict__ Vs)
{
    __shared__ __align__(16) char smem[32768];     // 2 x [128][64] bf16
    short* As = (short*)smem;                      // [128 rows][64 k]
    short* Bs = (short*)(smem + 16384);            // [128 d]   [64 k]
    float* st = (float*)smem;                      // epilogue: [128 n][33]

    const int tid = threadIdx.x;
    const int w   = tid >> 6;
    const int l   = tid & 63;
    const int q   = l >> 4;
    const int mrow= l & 15;
    const int wr  = w >> 1;
    const int wc  = w & 1;

    const int bx = blockIdx.x;
    const int m  = bx >> 2;               // 0=Q,1=K,2=V
    const int d0 = (bx & 3) * 128;
    const int r0 = blockIdx.y * 128;
    const int b  = r0 >> 12;
    const int n0 = r0 & 4095;

    const bf16*  W    = Wb + (size_t)m * (NC * NC);
    const float* bias = (m == 0) ? bq : (m == 1) ? bk : bv;
    bf16*        Out  = (m == 0) ? Qs : (m == 1) ? Ks : Vs;

    f32x4 acc[4][4];
    const f32x4 z = {0.f, 0.f, 0.f, 0.f};
    #pragma unroll
    for (int i = 0; i < 4; ++i)
        #pragma unroll
        for (int j = 0; j < 4; ++j) acc[i][j] = z;

    const int srow = tid >> 3;            // 0..31
    const int scol = (tid & 7) * 8;       // k elem 0,8,..,56

    for (int k0 = 0; k0 < NC; k0 += 64) {
        // ---- stage A, B tiles: 8x global_load_lds_dwordx4, no VGPR round-trip
        #pragma unroll
        for (int c = 0; c < 4; ++c) {
            int row = srow + 32 * c;
            GLL16(xb + (size_t)(r0 + row) * NC + k0 + scol, &As[row * 64 + scol]);
        }
        #pragma unroll
        for (int c = 0; c < 4; ++c) {
            int row = srow + 32 * c;
            GLL16(W + (size_t)(d0 + row) * NC + k0 + scol, &Bs[row * 64 + scol]);
        }
        __syncthreads();   // vmcnt(0) drain + barrier: tiles visible

        #pragma unroll
        for (int ks = 0; ks < 2; ++ks) {
            short8 af[4], bfr[4];
            #pragma unroll
            for (int ti = 0; ti < 4; ++ti)
                af[ti] = *(const short8*)&As[(64 * wr + 16 * ti + mrow) * 64 + q * 8 + 32 * ks];
            #pragma unroll
            for (int tj = 0; tj < 4; ++tj)
                bfr[tj] = *(const short8*)&Bs[(64 * wc + 16 * tj + mrow) * 64 + q * 8 + 32 * ks];
            #pragma unroll
            for (int ti = 0; ti < 4; ++ti)
                #pragma unroll
                for (int tj = 0; tj < 4; ++tj)
                    acc[ti][tj] = __builtin_amdgcn_mfma_f32_16x16x32_bf16(
                        af[ti], bfr[tj], acc[ti][tj], 0, 0, 0);
        }
        __syncthreads();
    }

    float bb[4];
    #pragma unroll
    for (int tj = 0; tj < 4; ++tj) bb[tj] = bias[d0 + 64 * wc + 16 * tj + mrow];

    #pragma unroll
    for (int dc = 0; dc < 4; ++dc) {
        if (wc == (dc >> 1)) {
            #pragma unroll
            for (int tjh = 0; tjh < 2; ++tjh) {
                int tj = 2 * (dc & 1) + tjh;
                #pragma unroll
                for (int ti = 0; ti < 4; ++ti)
                    #pragma unroll
                    for (int g = 0; g < 4; ++g) {
                        float v  = acc[ti][tj][g] + bb[tj];
                        float sg = 1.0f / (1.0f + __expf(-v));
                        int nl = 64 * wr + 16 * ti + 4 * q + g;
                        int dl = 16 * tjh + mrow;
                        st[nl * 33 + dl] = sg;
                    }
            }
        }
        __syncthreads();
        #pragma unroll
        for (int i = 0; i < 8; ++i) {
            int p     = tid + 256 * i;
            int dl    = p >> 6;
            int npair = tid & 63;
            bf162 v2;
            v2.x = __float2bfloat16(st[(2 * npair    ) * 33 + dl]);
            v2.y = __float2bfloat16(st[(2 * npair + 1) * 33 + dl]);
            size_t d = d0 + 32 * dc + dl;
            ((bf162*)(Out + ((size_t)b * NC + d) * NN + n0))[npair] = v2;
        }
        __syncthreads();
    }
}

// ---------------------------------------------------------------------------
// Kernel 2: MFMA attention. One block (4 waves) per (b,c).  (unchanged)
// ---------------------------------------------------------------------------
__global__ __launch_bounds__(256) void attn_mfma(
    const bf16* __restrict__ Qs, const bf16* __restrict__ Ks,
    const bf16* __restrict__ Vs, bf16* __restrict__ Os)
{
    __shared__ __align__(16) char smem[24064];
    bf16* VT  = (bf16*)smem;                         // [64][72]; later: OutS
    bf16* S1b = (bf16*)(smem + 9216);                // [64][40]
    bf16* S2b = (bf16*)(smem + 9216 + 5120);         // [32][72]
    bf16* KVT = (bf16*)(smem + 9216 + 5120 + 4608);  // [64][40]

    const int tid = threadIdx.x;
    const int w   = tid >> 6;     // wave 0..3 -> i-tile / ph-tile
    const int l   = tid & 63;
    const int m   = l & 15;       // A/B row within tile; C col within tile
    const int q   = l >> 4;       // k-quad; C row group
    const size_t base = (size_t)blockIdx.x * NN;   // blockIdx.x = b*C + c

    // ---- phase 1: V -> VT (bf16 transpose into LDS) ----
    {
        const uint4* src = (const uint4*)(Vs + base);
        #pragma unroll
        for (int v = 0; v < 2; ++v) {
            int e = tid + 256 * v;           // 0..511, covers 8 elems each
            uint4 r = src[e];
            bf16 tmp[8]; memcpy(tmp, &r, 16);
            int pw  = e >> 3;
            int ph0 = (e & 7) * 8;
            #pragma unroll
            for (int t = 0; t < 8; ++t)
                VT[(ph0 + t) * 72 + pw] = tmp[t];
        }
    }

    // ---- phase 2: T = Q K^T (rows 16w..16w+15, all 64 cols) ----
    f32x4 tacc[4];
    {
        const f32x4 z = {0.f, 0.f, 0.f, 0.f};
        short8 aQ[2];
        #pragma unroll
        for (int ks = 0; ks < 2; ++ks)
            aQ[ks] = *(const short8*)(Qs + base + (16 * w + m) * 64 + q * 8 + 32 * ks);
        #pragma unroll
        for (int tj = 0; tj < 4; ++tj) {
            tacc[tj] = z;
            #pragma unroll
            for (int ks = 0; ks < 2; ++ks) {
                short8 bK = *(const short8*)(Ks + base + (16 * tj + m) * 64 + q * 8 + 32 * ks);
                tacc[tj] = __builtin_amdgcn_mfma_f32_16x16x32_bf16(aQ[ks], bK, tacc[tj], 0, 0, 0);
            }
        }
    }

    // ---- phase 3a: S1 = softmax over col-pooled rows (32 logits/row) ----
    {
        float p[4][4], e[4][4], mx[4], s[4];
        #pragma unroll
        for (int r = 0; r < 4; ++r) mx[r] = -1e30f;
        #pragma unroll
        for (int t = 0; t < 4; ++t)
            #pragma unroll
            for (int r = 0; r < 4; ++r) {
                float v  = tacc[t][r];
                float pv = (v + __shfl_xor(v, 1)) * (0.5f * SCALE);  // pooled pair
                p[t][r] = pv;
                mx[r]   = fmaxf(mx[r], pv);
            }
        #pragma unroll
        for (int r = 0; r < 4; ++r) {
            #pragma unroll
            for (int d = 1; d < 16; d <<= 1)
                mx[r] = fmaxf(mx[r], __shfl_xor(mx[r], d));
            s[r] = 0.f;
        }
        #pragma unroll
        for (int t = 0; t < 4; ++t)
            #pragma unroll
            for (int r = 0; r < 4; ++r) {
                e[t][r] = __expf(p[t][r] - mx[r]);
                s[r] += e[t][r];
            }
        #pragma unroll
        for (int r = 0; r < 4; ++r) {
            #pragma unroll
            for (int d = 1; d < 16; d <<= 1)
                s[r] += __shfl_xor(s[r], d);
            s[r] = 2.0f / s[r];   // each jp counted twice in the lane reduction
        }
        if (!(l & 1)) {
            int jc = m >> 1;      // pooled col within tile (0..7)
            #pragma unroll
            for (int t = 0; t < 4; ++t)
                #pragma unroll
                for (int r = 0; r < 4; ++r)
                    S1b[(16 * w + q * 4 + r) * 40 + t * 8 + jc] =
                        __float2bfloat16(e[t][r] * s[r]);
        }
    }

    // ---- phase 3b: S2 = softmax over rows of row-pooled T (64 logits/row) ----
    {
        float p2[4][2], e2[4][2], mx[2], s[2];
        #pragma unroll
        for (int h = 0; h < 2; ++h) mx[h] = -1e30f;
        #pragma unroll
        for (int t = 0; t < 4; ++t)
            #pragma unroll
            for (int h = 0; h < 2; ++h) {
                float pv = (tacc[t][2 * h] + tacc[t][2 * h + 1]) * (0.5f * SCALE);
                p2[t][h] = pv;
                mx[h]    = fmaxf(mx[h], pv);
            }
        #pragma unroll
        for (int h = 0; h < 2; ++h) {
            #pragma unroll
            for (int d = 1; d < 16; d <<= 1)
                mx[h] = fmaxf(mx[h], __shfl_xor(mx[h], d));
            s[h] = 0.f;
        }
        #pragma unroll
        for (int t = 0; t < 4; ++t)
            #pragma unroll
            for (int h = 0; h < 2; ++h) {
                e2[t][h] = __expf(p2[t][h] - mx[h]);
                s[h] += e2[t][h];
            }
        #pragma unroll
        for (int h = 0; h < 2; ++h) {
            #pragma unroll
            for (int d = 1; d < 16; d <<= 1)
                s[h] += __shfl_xor(s[h], d);
            s[h] = 1.0f / s[h];
        }
        #pragma unroll
        for (int t = 0; t < 4; ++t)
            #pragma unroll
            for (int h = 0; h < 2; ++h)
                S2b[(8 * w + q * 2 + h) * 72 + t * 16 + m] =
                    __float2bfloat16(e2[t][h] * s[h]);
    }
    __syncthreads();   // VT, S1b, S2b now visible to all waves

    // ---- phase 4: KVT[ph][ip] = sum_j VT[ph][j] * S2[ip][j] ----
    {
        short8 aV[2];
        #pragma unroll
        for (int ks = 0; ks < 2; ++ks)
            aV[ks] = *(const short8*)&VT[(16 * w + m) * 72 + q * 8 + 32 * ks];
        #pragma unroll
        for (int tn = 0; tn < 2; ++tn) {
            f32x4 kacc = {0.f, 0.f, 0.f, 0.f};
            #pragma unroll
            for (int ks = 0; ks < 2; ++ks) {
                short8 bS = *(const short8*)&S2b[(16 * tn + m) * 72 + q * 8 + 32 * ks];
                kacc = __builtin_amdgcn_mfma_f32_16x16x32_bf16(aV[ks], bS, kacc, 0, 0, 0);
            }
            #pragma unroll
            for (int r = 0; r < 4; ++r)
                KVT[(16 * w + q * 4 + r) * 40 + 16 * tn + m] = __float2bfloat16(kacc[r]);
        }
    }
    __syncthreads();   // KVT visible; all VT reads complete

    // ---- phase 5: out[i][ph] = sum_jp S1[i][jp] * KVT[ph][jp] ----
    f32x4 oacc[4];
    {
        short8 aS = *(const short8*)&S1b[(16 * w + m) * 40 + q * 8];
        #pragma unroll
        for (int tn = 0; tn < 4; ++tn) {
            short8 bKV = *(const short8*)&KVT[(16 * tn + m) * 40 + q * 8];
            f32x4 z = {0.f, 0.f, 0.f, 0.f};
            oacc[tn] = __builtin_amdgcn_mfma_f32_16x16x32_bf16(aS, bKV, z, 0, 0, 0);
        }
    }

    // ---- phase 6: stage out (bf16) into VT region, then coalesced store ----
    {
        bf16* OutS = VT;   // [64][72], VT dead (all reads before last barrier)
        #pragma unroll
        for (int tn = 0; tn < 4; ++tn)
            #pragma unroll
            for (int r = 0; r < 4; ++r)
                OutS[(16 * w + q * 4 + r) * 72 + 16 * tn + m] = __float2bfloat16(oacc[tn][r]);
        __syncthreads();
        uint* Og = (uint*)(Os + base);
        #pragma unroll
        for (int v = 0; v < 8; ++v) {
            int e  = tid + 256 * v;    // 0..2047
            int i  = e >> 5;
            int pp = e & 31;
            Og[e] = *(uint*)&OutS[i * 72 + 2 * pp];
        }
    }
}

// ---------------------------------------------------------------------------
// Kernel 3: spatial [B,C,N] (bf16) -> [B,N,C] (f32) tiled transpose.
// ---------------------------------------------------------------------------
__global__ __launch_bounds__(256) void unspat_kernel(
    const bf16* __restrict__ Os, float* __restrict__ out)
{
    __shared__ float t[32][65];
    const int b  = blockIdx.z;
    const int c0 = blockIdx.y * 32;
    const int n0 = blockIdx.x * 64;
    const int tx = threadIdx.x & 31;
    const int ty = threadIdx.x >> 5;
    const bf162* src = (const bf162*)(Os + ((size_t)b * NC + c0) * NN + n0);
    #pragma unroll
    for (int r = 0; r < 4; ++r) {
        int cc = ty + r * 8;
        float2 f = __bfloat1622float2(src[(size_t)cc * (NN/2) + tx]);
        t[cc][2*tx] = f.x; t[cc][2*tx+1] = f.y;
    }
    __syncthreads();
    float* dst = out + ((size_t)b * NN + n0) * NC + c0;
    #pragma unroll
    for (int r = 0; r < 8; ++r) {
        int nn = ty + r * 8;
        dst[(size_t)nn * NC + tx] = t[tx][nn];
    }
}

// ---------------------------------------------------------------------------
extern "C" void kernel_launch(void* const* d_in, const int* in_sizes, int n_in,
                              void* d_out, int out_size, void* d_ws, size_t ws_size,
                              hipStream_t stream)
{
    const float* x  = (const float*)d_in[0];
    const float* Wq = (const float*)d_in[1];
    const float* bq = (const float*)d_in[2];
    const float* Wk = (const float*)d_in[3];
    const float* bk = (const float*)d_in[4];
    const float* Wv = (const float*)d_in[5];
    const float* bv = (const float*)d_in[6];
    float* out = (float*)d_out;

    const size_t S = (size_t)NB * NC * NN;   // 33,554,432 elems per tensor
    bf16* Qb = (bf16*)d_ws;                  // ws >= 3*S*2 = 201,326,592 B
    bf16* Kb = Qb + S;
    bf16* Vb = Kb + S;
    bf16* xb = (bf16*)d_out;                 // dead until unspat overwrites
    bf16* Wb = ((bf16*)d_out) + S;           // 1.5 MB, in d_out spare space

    cast_x_kernel<<<dim3((NB * NN * NC) / (256 * 8)), 256, 0, stream>>>(x, xb);
    cast_w_kernel<<<dim3((NC * NC) / (256 * 8), 3), 256, 0, stream>>>(Wq, Wk, Wv, Wb);
    proj_mfma<<<dim3(12, (NB * NN) / 128), 256, 0, stream>>>(
        xb, Wb, bq, bk, bv, Qb, Kb, Vb);
    // attention writes its output into the Q region (each block's slice is
    // disjoint and its Q reads complete before its writes).
    attn_mfma<<<dim3(NB * NC), 256, 0, stream>>>(Qb, Kb, Vb, Qb);
    unspat_kernel<<<dim3(NN / 64, NC / 32, NB), 256, 0, stream>>>(Qb, out);
}

// Round 2
// 522.304 us; speedup vs baseline: 1.1098x; 1.0608x over previous
//
#include <hip/hip_runtime.h>
#include <hip/hip_bf16.h>
#include <string.h>

typedef __hip_bfloat16  bf16;
typedef __hip_bfloat162 bf162;
typedef __attribute__((ext_vector_type(8))) short short8;
typedef __attribute__((ext_vector_type(4))) float f32x4;

#define NB 16
#define NN 4096
#define NC 512
#define SCALE 0.044194173824159216f  // 1/sqrt(512)

// Direct global->LDS DMA, 16B per lane. LDS dest must be linear in lane order.
#define GLL16(gp, lp) __builtin_amdgcn_global_load_lds( \
    (__attribute__((address_space(1))) void*)(gp),      \
    (__attribute__((address_space(3))) void*)(lp), 16, 0, 0)

// ---------------------------------------------------------------------------
// Kernel 0: cast x [65536,512] fp32 -> bf16 (into d_out region, dead there
// until unspat_kernel overwrites it at the end).
// ---------------------------------------------------------------------------
__global__ __launch_bounds__(256) void cast_x_kernel(
    const float* __restrict__ x, bf16* __restrict__ xb)
{
    size_t i = ((size_t)blockIdx.x * 256 + threadIdx.x) * 8;
    float4 a = *(const float4*)(x + i);
    float4 b = *(const float4*)(x + i + 4);
    bf16 t[8];
    t[0] = __float2bfloat16(a.x); t[1] = __float2bfloat16(a.y);
    t[2] = __float2bfloat16(a.z); t[3] = __float2bfloat16(a.w);
    t[4] = __float2bfloat16(b.x); t[5] = __float2bfloat16(b.y);
    t[6] = __float2bfloat16(b.z); t[7] = __float2bfloat16(b.w);
    uint4 r; memcpy(&r, t, 16);
    *(uint4*)(xb + i) = r;
}

// ---------------------------------------------------------------------------
// Kernel 0b: cast Wq/Wk/Wv [512,512] fp32 -> bf16 once.
// ---------------------------------------------------------------------------
__global__ __launch_bounds__(256) void cast_w_kernel(
    const float* __restrict__ Wq, const float* __restrict__ Wk,
    const float* __restrict__ Wv, bf16* __restrict__ Wb)
{
    const float* W = (blockIdx.y == 0) ? Wq : (blockIdx.y == 1) ? Wk : Wv;
    size_t i = ((size_t)blockIdx.x * 256 + threadIdx.x) * 8;
    float4 a = *(const float4*)(W + i);
    float4 b = *(const float4*)(W + i + 4);
    bf16 t[8];
    t[0] = __float2bfloat16(a.x); t[1] = __float2bfloat16(a.y);
    t[2] = __float2bfloat16(a.z); t[3] = __float2bfloat16(a.w);
    t[4] = __float2bfloat16(b.x); t[5] = __float2bfloat16(b.y);
    t[6] = __float2bfloat16(b.z); t[7] = __float2bfloat16(b.w);
    uint4 r; memcpy(&r, t, 16);
    *(uint4*)(Wb + (size_t)blockIdx.y * (NC * NC) + i) = r;
}

// ---------------------------------------------------------------------------
// Kernel 1: MFMA projection  y = sigmoid(xb @ W^T + b) -> spatial [B,C,N] bf16.
// m97 structure + XOR-swizzled LDS (linear GLL dest, pre-swizzled global src
// column, same XOR on frag reads) + single-pass bf16 transposed epilogue.
// ---------------------------------------------------------------------------
__global__ __launch_bounds__(256) void proj_mfma(
    const bf16* __restrict__ xb, const bf16* __restrict__ Wb,
    const float* __restrict__ bq, const float* __restrict__ bk,
    const float* __restrict__ bv,
    bf16* __restrict__ Qs, bf16* __restrict__ Ks, bf16* __restrict__ Vs)
{
    __shared__ __align__(16) char smem[36864];     // K-loop: 2x[128][64] bf16
    short* As = (short*)smem;                      // [128 rows][64 k] (swz)
    short* Bs = (short*)(smem + 16384);            // [128 d]   [64 k] (swz)
    bf16*  OutS = (bf16*)smem;                     // epilogue: [128 d][144]

    const int tid = threadIdx.x;
    const int w   = tid >> 6;
    const int l   = tid & 63;
    const int q   = l >> 4;
    const int mrow= l & 15;
    const int wr  = w >> 1;
    const int wc  = w & 1;

    const int bx = blockIdx.x;
    const int m  = bx >> 2;               // 0=Q,1=K,2=V
    const int d0 = (bx & 3) * 128;
    const int r0 = blockIdx.y * 128;
    const int b  = r0 >> 12;
    const int n0 = r0 & 4095;

    const bf16*  W    = Wb + (size_t)m * (NC * NC);
    const float* bias = (m == 0) ? bq : (m == 1) ? bk : bv;
    bf16*        Out  = (m == 0) ? Qs : (m == 1) ? Ks : Vs;

    f32x4 acc[4][4];
    const f32x4 z = {0.f, 0.f, 0.f, 0.f};
    #pragma unroll
    for (int i = 0; i < 4; ++i)
        #pragma unroll
        for (int j = 0; j < 4; ++j) acc[i][j] = z;

    const int srow = tid >> 3;                      // 0..31
    const int scol = (tid & 7) * 8;                 // linear LDS col (elems)
    const int sxor = ((tid ^ (tid >> 3)) & 7) * 8;  // swizzled SOURCE col
    const int axor = (mrow & 7) * 8;                // frag-read XOR (elems)

    for (int k0 = 0; k0 < NC; k0 += 64) {
        #pragma unroll
        for (int c = 0; c < 4; ++c) {
            int row = srow + 32 * c;
            GLL16(xb + (size_t)(r0 + row) * NC + k0 + sxor, &As[row * 64 + scol]);
        }
        #pragma unroll
        for (int c = 0; c < 4; ++c) {
            int row = srow + 32 * c;
            GLL16(W + (size_t)(d0 + row) * NC + k0 + sxor, &Bs[row * 64 + scol]);
        }
        __syncthreads();   // vmcnt(0) drain + barrier: tiles visible

        #pragma unroll
        for (int ks = 0; ks < 2; ++ks) {
            short8 af[4], bfr[4];
            #pragma unroll
            for (int ti = 0; ti < 4; ++ti)
                af[ti] = *(const short8*)&As[(64 * wr + 16 * ti + mrow) * 64 +
                                             ((q * 8 + 32 * ks) ^ axor)];
            #pragma unroll
            for (int tj = 0; tj < 4; ++tj)
                bfr[tj] = *(const short8*)&Bs[(64 * wc + 16 * tj + mrow) * 64 +
                                              ((q * 8 + 32 * ks) ^ axor)];
            #pragma unroll
            for (int ti = 0; ti < 4; ++ti)
                #pragma unroll
                for (int tj = 0; tj < 4; ++tj)
                    acc[ti][tj] = __builtin_amdgcn_mfma_f32_16x16x32_bf16(
                        af[ti], bfr[tj], acc[ti][tj], 0, 0, 0);
        }
        __syncthreads();
    }

    // ---- single-pass epilogue: sigmoid -> bf16 [d][n] staging -> uint4 store
    float bb[4];
    #pragma unroll
    for (int tj = 0; tj < 4; ++tj) bb[tj] = bias[d0 + 64 * wc + 16 * tj + mrow];

    #pragma unroll
    for (int ti = 0; ti < 4; ++ti)
        #pragma unroll
        for (int tj = 0; tj < 4; ++tj) {
            int d = 64 * wc + 16 * tj + mrow;
            bf16 t4[4];
            #pragma unroll
            for (int g = 0; g < 4; ++g) {
                float v = acc[ti][tj][g] + bb[tj];
                t4[g] = __float2bfloat16(1.0f / (1.0f + __expf(-v)));
            }
            uint2 pk; memcpy(&pk, t4, 8);
            // n-chunk = 64*wr + 16*ti + 4*q (4 consecutive n via g)
            *(uint2*)&OutS[d * 144 + 64 * wr + 16 * ti + 4 * q] = pk;
        }
    __syncthreads();

    #pragma unroll
    for (int v = 0; v < 8; ++v) {
        int e  = tid + 256 * v;   // 0..2047
        int d  = e >> 4;          // 0..127
        int ch = e & 15;          // 16B chunk along n
        uint4 r = *(const uint4*)&OutS[d * 144 + ch * 8];
        *(uint4*)(Out + ((size_t)b * NC + d0 + d) * NN + n0 + ch * 8) = r;
    }
}

// ---------------------------------------------------------------------------
// Kernel 2: MFMA attention. One block (4 waves) per (b,c).
// Phase 1 now does the V transpose in registers (8x8 shfl_xor butterfly) and
// writes VT with uint4 (bank-optimal: slot = ph mod 8). Phases 2-6 unchanged.
// ---------------------------------------------------------------------------
__global__ __launch_bounds__(256) void attn_mfma(
    const bf16* __restrict__ Qs, const bf16* __restrict__ Ks,
    const bf16* __restrict__ Vs, bf16* __restrict__ Os)
{
    __shared__ __align__(16) char smem[24064];
    bf16* VT  = (bf16*)smem;                         // [64][72]; later: OutS
    bf16* S1b = (bf16*)(smem + 9216);                // [64][40]
    bf16* S2b = (bf16*)(smem + 9216 + 5120);         // [32][72]
    bf16* KVT = (bf16*)(smem + 9216 + 5120 + 4608);  // [64][40]

    const int tid = threadIdx.x;
    const int w   = tid >> 6;     // wave 0..3 -> i-tile / ph-tile
    const int l   = tid & 63;
    const int m   = l & 15;       // A/B row within tile; C col within tile
    const int q   = l >> 4;       // k-quad; C row group
    const size_t base = (size_t)blockIdx.x * NN;   // blockIdx.x = b*C + c

    // ---- phase 1: V -> VT via in-register 8x8 transpose ----
    {
        const int g = l >> 3;          // row-in-block / transpose lane index
        #pragma unroll
        for (int v = 0; v < 2; ++v) {
            int pw  = 8 * w + g + 32 * v;       // V row this thread loads
            int ph0 = (l & 7) * 8;              // ph block
            uint4 r4 = *(const uint4*)(Vs + base + pw * 64 + ph0);
            ushort r[8]; memcpy(r, &r4, 16);
            // 8x8 transpose across lanes {l&7 fixed, g=0..7} (stride-8 lanes)
            #pragma unroll
            for (int mm = 1; mm < 8; mm <<= 1) {
                const bool hi = (g & mm) != 0;
                #pragma unroll
                for (int j0 = 0; j0 < 8; ++j0) {
                    if (!(j0 & mm)) {
                        const int j1 = j0 | mm;
                        int t = hi ? (int)r[j0] : (int)r[j1];
                        t = __shfl_xor(t, mm << 3, 64);
                        if (hi) r[j0] = (ushort)t; else r[j1] = (ushort)t;
                    }
                }
            }
            // lane now holds VT row ph = ph0 + g, pw block 8w+32v..+7
            uint4 wv; memcpy(&wv, r, 16);
            *(uint4*)&VT[(ph0 + g) * 72 + 8 * w + 32 * v] = wv;
        }
    }

    // ---- phase 2: T = Q K^T (rows 16w..16w+15, all 64 cols) ----
    f32x4 tacc[4];
    {
        const f32x4 z = {0.f, 0.f, 0.f, 0.f};
        short8 aQ[2];
        #pragma unroll
        for (int ks = 0; ks < 2; ++ks)
            aQ[ks] = *(const short8*)(Qs + base + (16 * w + m) * 64 + q * 8 + 32 * ks);
        #pragma unroll
        for (int tj = 0; tj < 4; ++tj) {
            tacc[tj] = z;
            #pragma unroll
            for (int ks = 0; ks < 2; ++ks) {
                short8 bK = *(const short8*)(Ks + base + (16 * tj + m) * 64 + q * 8 + 32 * ks);
                tacc[tj] = __builtin_amdgcn_mfma_f32_16x16x32_bf16(aQ[ks], bK, tacc[tj], 0, 0, 0);
            }
        }
    }

    // ---- phase 3a: S1 = softmax over col-pooled rows (32 logits/row) ----
    {
        float p[4][4], e[4][4], mx[4], s[4];
        #pragma unroll
        for (int r = 0; r < 4; ++r) mx[r] = -1e30f;
        #pragma unroll
        for (int t = 0; t < 4; ++t)
            #pragma unroll
            for (int r = 0; r < 4; ++r) {
                float v  = tacc[t][r];
                float pv = (v + __shfl_xor(v, 1)) * (0.5f * SCALE);  // pooled pair
                p[t][r] = pv;
                mx[r]   = fmaxf(mx[r], pv);
            }
        #pragma unroll
        for (int r = 0; r < 4; ++r) {
            #pragma unroll
            for (int d = 1; d < 16; d <<= 1)
                mx[r] = fmaxf(mx[r], __shfl_xor(mx[r], d));
            s[r] = 0.f;
        }
        #pragma unroll
        for (int t = 0; t < 4; ++t)
            #pragma unroll
            for (int r = 0; r < 4; ++r) {
                e[t][r] = __expf(p[t][r] - mx[r]);
                s[r] += e[t][r];
            }
        #pragma unroll
        for (int r = 0; r < 4; ++r) {
            #pragma unroll
            for (int d = 1; d < 16; d <<= 1)
                s[r] += __shfl_xor(s[r], d);
            s[r] = 2.0f / s[r];   // each jp counted twice in the lane reduction
        }
        if (!(l & 1)) {
            int jc = m >> 1;      // pooled col within tile (0..7)
            #pragma unroll
            for (int t = 0; t < 4; ++t)
                #pragma unroll
                for (int r = 0; r < 4; ++r)
                    S1b[(16 * w + q * 4 + r) * 40 + t * 8 + jc] =
                        __float2bfloat16(e[t][r] * s[r]);
        }
    }

    // ---- phase 3b: S2 = softmax over rows of row-pooled T (64 logits/row) ----
    {
        float p2[4][2], e2[4][2], mx[2], s[2];
        #pragma unroll
        for (int h = 0; h < 2; ++h) mx[h] = -1e30f;
        #pragma unroll
        for (int t = 0; t < 4; ++t)
            #pragma unroll
            for (int h = 0; h < 2; ++h) {
                float pv = (tacc[t][2 * h] + tacc[t][2 * h + 1]) * (0.5f * SCALE);
                p2[t][h] = pv;
                mx[h]    = fmaxf(mx[h], pv);
            }
        #pragma unroll
        for (int h = 0; h < 2; ++h) {
            #pragma unroll
            for (int d = 1; d < 16; d <<= 1)
                mx[h] = fmaxf(mx[h], __shfl_xor(mx[h], d));
            s[h] = 0.f;
        }
        #pragma unroll
        for (int t = 0; t < 4; ++t)
            #pragma unroll
            for (int h = 0; h < 2; ++h) {
                e2[t][h] = __expf(p2[t][h] - mx[h]);
                s[h] += e2[t][h];
            }
        #pragma unroll
        for (int h = 0; h < 2; ++h) {
            #pragma unroll
            for (int d = 1; d < 16; d <<= 1)
                s[h] += __shfl_xor(s[h], d);
            s[h] = 1.0f / s[h];
        }
        #pragma unroll
        for (int t = 0; t < 4; ++t)
            #pragma unroll
            for (int h = 0; h < 2; ++h)
                S2b[(8 * w + q * 2 + h) * 72 + t * 16 + m] =
                    __float2bfloat16(e2[t][h] * s[h]);
    }
    __syncthreads();   // VT, S1b, S2b now visible to all waves

    // ---- phase 4: KVT[ph][ip] = sum_j VT[ph][j] * S2[ip][j] ----
    {
        short8 aV[2];
        #pragma unroll
        for (int ks = 0; ks < 2; ++ks)
            aV[ks] = *(const short8*)&VT[(16 * w + m) * 72 + q * 8 + 32 * ks];
        #pragma unroll
        for (int tn = 0; tn < 2; ++tn) {
            f32x4 kacc = {0.f, 0.f, 0.f, 0.f};
            #pragma unroll
            for (int ks = 0; ks < 2; ++ks) {
                short8 bS = *(const short8*)&S2b[(16 * tn + m) * 72 + q * 8 + 32 * ks];
                kacc = __builtin_amdgcn_mfma_f32_16x16x32_bf16(aV[ks], bS, kacc, 0, 0, 0);
            }
            #pragma unroll
            for (int r = 0; r < 4; ++r)
                KVT[(16 * w + q * 4 + r) * 40 + 16 * tn + m] = __float2bfloat16(kacc[r]);
        }
    }
    __syncthreads();   // KVT visible; all VT reads complete

    // ---- phase 5: out[i][ph] = sum_jp S1[i][jp] * KVT[ph][jp] ----
    f32x4 oacc[4];
    {
        short8 aS = *(const short8*)&S1b[(16 * w + m) * 40 + q * 8];
        #pragma unroll
        for (int tn = 0; tn < 4; ++tn) {
            short8 bKV = *(const short8*)&KVT[(16 * tn + m) * 40 + q * 8];
            f32x4 z = {0.f, 0.f, 0.f, 0.f};
            oacc[tn] = __builtin_amdgcn_mfma_f32_16x16x32_bf16(aS, bKV, z, 0, 0, 0);
        }
    }

    // ---- phase 6: stage out (bf16) into VT region, then coalesced store ----
    {
        bf16* OutS = VT;   // [64][72], VT dead (all reads before last barrier)
        #pragma unroll
        for (int tn = 0; tn < 4; ++tn)
            #pragma unroll
            for (int r = 0; r < 4; ++r)
                OutS[(16 * w + q * 4 + r) * 72 + 16 * tn + m] = __float2bfloat16(oacc[tn][r]);
        __syncthreads();
        uint* Og = (uint*)(Os + base);
        #pragma unroll
        for (int v = 0; v < 8; ++v) {
            int e  = tid + 256 * v;    // 0..2047
            int i  = e >> 5;
            int pp = e & 31;
            Og[e] = *(uint*)&OutS[i * 72 + 2 * pp];
        }
    }
}

// ---------------------------------------------------------------------------
// Kernel 3: spatial [B,C,N] (bf16) -> [B,N,C] (f32) tiled transpose.
// ---------------------------------------------------------------------------
__global__ __launch_bounds__(256) void unspat_kernel(
    const bf16* __restrict__ Os, float* __restrict__ out)
{
    __shared__ float t[32][65];
    const int b  = blockIdx.z;
    const int c0 = blockIdx.y * 32;
    const int n0 = blockIdx.x * 64;
    const int tx = threadIdx.x & 31;
    const int ty = threadIdx.x >> 5;
    const bf162* src = (const bf162*)(Os + ((size_t)b * NC + c0) * NN + n0);
    #pragma unroll
    for (int r = 0; r < 4; ++r) {
        int cc = ty + r * 8;
        float2 f = __bfloat1622float2(src[(size_t)cc * (NN/2) + tx]);
        t[cc][2*tx] = f.x; t[cc][2*tx+1] = f.y;
    }
    __syncthreads();
    float* dst = out + ((size_t)b * NN + n0) * NC + c0;
    #pragma unroll
    for (int r = 0; r < 8; ++r) {
        int nn = ty + r * 8;
        dst[(size_t)nn * NC + tx] = t[tx][nn];
    }
}

// ---------------------------------------------------------------------------
extern "C" void kernel_launch(void* const* d_in, const int* in_sizes, int n_in,
                              void* d_out, int out_size, void* d_ws, size_t ws_size,
                              hipStream_t stream)
{
    const float* x  = (const float*)d_in[0];
    const float* Wq = (const float*)d_in[1];
    const float* bq = (const float*)d_in[2];
    const float* Wk = (const float*)d_in[3];
    const float* bk = (const float*)d_in[4];
    const float* Wv = (const float*)d_in[5];
    const float* bv = (const float*)d_in[6];
    float* out = (float*)d_out;

    const size_t S = (size_t)NB * NC * NN;   // 33,554,432 elems per tensor
    bf16* Qb = (bf16*)d_ws;                  // ws >= 3*S*2 = 201,326,592 B
    bf16* Kb = Qb + S;
    bf16* Vb = Kb + S;
    bf16* xb = (bf16*)d_out;                 // dead until unspat overwrites
    bf16* Wb = ((bf16*)d_out) + S;           // 1.5 MB, in d_out spare space

    cast_x_kernel<<<dim3((NB * NN * NC) / (256 * 8)), 256, 0, stream>>>(x, xb);
    cast_w_kernel<<<dim3((NC * NC) / (256 * 8), 3), 256, 0, stream>>>(Wq, Wk, Wv, Wb);
    proj_mfma<<<dim3(12, (NB * NN) / 128), 256, 0, stream>>>(
        xb, Wb, bq, bk, bv, Qb, Kb, Vb);
    // attention writes its output into the Q region (each block's slice is
    // disjoint and its Q reads complete before its writes).
    attn_mfma<<<dim3(NB * NC), 256, 0, stream>>>(Qb, Kb, Vb, Qb);
    unspat_kernel<<<dim3(NN / 64, NC / 32, NB), 256, 0, stream>>>(Qb, out);
}

// Round 3
// 495.350 us; speedup vs baseline: 1.1701x; 1.0544x over previous
//
#include <hip/hip_runtime.h>
#include <hip/hip_bf16.h>
#include <string.h>

typedef __hip_bfloat16  bf16;
typedef __hip_bfloat162 bf162;
typedef __attribute__((ext_vector_type(8))) short short8;
typedef __attribute__((ext_vector_type(4))) float f32x4;

#define NB 16
#define NN 4096
#define NC 512
#define SCALE 0.044194173824159216f  // 1/sqrt(512)

// Direct global->LDS DMA, 16B per lane. LDS dest must be linear in lane order.
#define GLL16(gp, lp) __builtin_amdgcn_global_load_lds( \
    (__attribute__((address_space(1))) void*)(gp),      \
    (__attribute__((address_space(3))) void*)(lp), 16, 0, 0)

// ---------------------------------------------------------------------------
// Kernel 0: cast x [65536,512] fp32 -> bf16 (into d_out region, dead there
// until unspat_kernel overwrites it at the end).
// ---------------------------------------------------------------------------
__global__ __launch_bounds__(256) void cast_x_kernel(
    const float* __restrict__ x, bf16* __restrict__ xb)
{
    size_t i = ((size_t)blockIdx.x * 256 + threadIdx.x) * 8;
    float4 a = *(const float4*)(x + i);
    float4 b = *(const float4*)(x + i + 4);
    bf16 t[8];
    t[0] = __float2bfloat16(a.x); t[1] = __float2bfloat16(a.y);
    t[2] = __float2bfloat16(a.z); t[3] = __float2bfloat16(a.w);
    t[4] = __float2bfloat16(b.x); t[5] = __float2bfloat16(b.y);
    t[6] = __float2bfloat16(b.z); t[7] = __float2bfloat16(b.w);
    uint4 r; memcpy(&r, t, 16);
    *(uint4*)(xb + i) = r;
}

// ---------------------------------------------------------------------------
// Kernel 0b: cast Wq/Wk/Wv [512,512] fp32 -> bf16 once.
// ---------------------------------------------------------------------------
__global__ __launch_bounds__(256) void cast_w_kernel(
    const float* __restrict__ Wq, const float* __restrict__ Wk,
    const float* __restrict__ Wv, bf16* __restrict__ Wb)
{
    const float* W = (blockIdx.y == 0) ? Wq : (blockIdx.y == 1) ? Wk : Wv;
    size_t i = ((size_t)blockIdx.x * 256 + threadIdx.x) * 8;
    float4 a = *(const float4*)(W + i);
    float4 b = *(const float4*)(W + i + 4);
    bf16 t[8];
    t[0] = __float2bfloat16(a.x); t[1] = __float2bfloat16(a.y);
    t[2] = __float2bfloat16(a.z); t[3] = __float2bfloat16(a.w);
    t[4] = __float2bfloat16(b.x); t[5] = __float2bfloat16(b.y);
    t[6] = __float2bfloat16(b.z); t[7] = __float2bfloat16(b.w);
    uint4 r; memcpy(&r, t, 16);
    *(uint4*)(Wb + (size_t)blockIdx.y * (NC * NC) + i) = r;
}

// ---------------------------------------------------------------------------
// Kernel 1: MFMA projection  y = sigmoid(xb @ W^T + b) -> spatial [B,C,N] bf16.
// m97 structure + XOR-swizzled LDS (linear GLL dest, pre-swizzled global src
// column, same XOR on frag reads) + single-pass bf16 transposed epilogue.
// (unchanged from round 2: 200 us, conflicts 5.5e6, MfmaUtil 22%)
// ---------------------------------------------------------------------------
__global__ __launch_bounds__(256) void proj_mfma(
    const bf16* __restrict__ xb, const bf16* __restrict__ Wb,
    const float* __restrict__ bq, const float* __restrict__ bk,
    const float* __restrict__ bv,
    bf16* __restrict__ Qs, bf16* __restrict__ Ks, bf16* __restrict__ Vs)
{
    __shared__ __align__(16) char smem[36864];     // K-loop: 2x[128][64] bf16
    short* As = (short*)smem;                      // [128 rows][64 k] (swz)
    short* Bs = (short*)(smem + 16384);            // [128 d]   [64 k] (swz)
    bf16*  OutS = (bf16*)smem;                     // epilogue: [128 d][144]

    const int tid = threadIdx.x;
    const int w   = tid >> 6;
    const int l   = tid & 63;
    const int q   = l >> 4;
    const int mrow= l & 15;
    const int wr  = w >> 1;
    const int wc  = w & 1;

    const int bx = blockIdx.x;
    const int m  = bx >> 2;               // 0=Q,1=K,2=V
    const int d0 = (bx & 3) * 128;
    const int r0 = blockIdx.y * 128;
    const int b  = r0 >> 12;
    const int n0 = r0 & 4095;

    const bf16*  W    = Wb + (size_t)m * (NC * NC);
    const float* bias = (m == 0) ? bq : (m == 1) ? bk : bv;
    bf16*        Out  = (m == 0) ? Qs : (m == 1) ? Ks : Vs;

    f32x4 acc[4][4];
    const f32x4 z = {0.f, 0.f, 0.f, 0.f};
    #pragma unroll
    for (int i = 0; i < 4; ++i)
        #pragma unroll
        for (int j = 0; j < 4; ++j) acc[i][j] = z;

    const int srow = tid >> 3;                      // 0..31
    const int scol = (tid & 7) * 8;                 // linear LDS col (elems)
    const int sxor = ((tid ^ (tid >> 3)) & 7) * 8;  // swizzled SOURCE col
    const int axor = (mrow & 7) * 8;                // frag-read XOR (elems)

    for (int k0 = 0; k0 < NC; k0 += 64) {
        #pragma unroll
        for (int c = 0; c < 4; ++c) {
            int row = srow + 32 * c;
            GLL16(xb + (size_t)(r0 + row) * NC + k0 + sxor, &As[row * 64 + scol]);
        }
        #pragma unroll
        for (int c = 0; c < 4; ++c) {
            int row = srow + 32 * c;
            GLL16(W + (size_t)(d0 + row) * NC + k0 + sxor, &Bs[row * 64 + scol]);
        }
        __syncthreads();   // vmcnt(0) drain + barrier: tiles visible

        #pragma unroll
        for (int ks = 0; ks < 2; ++ks) {
            short8 af[4], bfr[4];
            #pragma unroll
            for (int ti = 0; ti < 4; ++ti)
                af[ti] = *(const short8*)&As[(64 * wr + 16 * ti + mrow) * 64 +
                                             ((q * 8 + 32 * ks) ^ axor)];
            #pragma unroll
            for (int tj = 0; tj < 4; ++tj)
                bfr[tj] = *(const short8*)&Bs[(64 * wc + 16 * tj + mrow) * 64 +
                                              ((q * 8 + 32 * ks) ^ axor)];
            #pragma unroll
            for (int ti = 0; ti < 4; ++ti)
                #pragma unroll
                for (int tj = 0; tj < 4; ++tj)
                    acc[ti][tj] = __builtin_amdgcn_mfma_f32_16x16x32_bf16(
                        af[ti], bfr[tj], acc[ti][tj], 0, 0, 0);
        }
        __syncthreads();
    }

    // ---- single-pass epilogue: sigmoid -> bf16 [d][n] staging -> uint4 store
    float bb[4];
    #pragma unroll
    for (int tj = 0; tj < 4; ++tj) bb[tj] = bias[d0 + 64 * wc + 16 * tj + mrow];

    #pragma unroll
    for (int ti = 0; ti < 4; ++ti)
        #pragma unroll
        for (int tj = 0; tj < 4; ++tj) {
            int d = 64 * wc + 16 * tj + mrow;
            bf16 t4[4];
            #pragma unroll
            for (int g = 0; g < 4; ++g) {
                float v = acc[ti][tj][g] + bb[tj];
                t4[g] = __float2bfloat16(1.0f / (1.0f + __expf(-v)));
            }
            uint2 pk; memcpy(&pk, t4, 8);
            // n-chunk = 64*wr + 16*ti + 4*q (4 consecutive n via g)
            *(uint2*)&OutS[d * 144 + 64 * wr + 16 * ti + 4 * q] = pk;
        }
    __syncthreads();

    #pragma unroll
    for (int v = 0; v < 8; ++v) {
        int e  = tid + 256 * v;   // 0..2047
        int d  = e >> 4;          // 0..127
        int ch = e & 15;          // 16B chunk along n
        uint4 r = *(const uint4*)&OutS[d * 144 + ch * 8];
        *(uint4*)(Out + ((size_t)b * NC + d0 + d) * NN + n0 + ch * 8) = r;
    }
}

// ---------------------------------------------------------------------------
// Kernel 2: MFMA attention. One block (4 waves) per (b,c).
// Phase 1: scalar V transpose with XOR column-block swizzle keyed on ph>>3
//   (write banks = 36t + 4a + pw/2 -> all 32 banks, 2 lanes each = free;
//   the round-1 unswizzled version was 16-way, the round-2 shfl version was
//   VALU-bound). Phase 4 reads apply the same XOR; b128 slice balance is
//   unchanged (8 lanes per 4-bank slice = optimum).
// T5: s_setprio(1) around MFMA clusters (m191: +4-7% on attn).
// ---------------------------------------------------------------------------
__global__ __launch_bounds__(256) void attn_mfma(
    const bf16* __restrict__ Qs, const bf16* __restrict__ Ks,
    const bf16* __restrict__ Vs, bf16* __restrict__ Os)
{
    __shared__ __align__(16) char smem[24064];
    bf16* VT  = (bf16*)smem;                         // [64][72] swz; later OutS
    bf16* S1b = (bf16*)(smem + 9216);                // [64][40]
    bf16* S2b = (bf16*)(smem + 9216 + 5120);         // [32][72]
    bf16* KVT = (bf16*)(smem + 9216 + 5120 + 4608);  // [64][40]

    const int tid = threadIdx.x;
    const int w   = tid >> 6;     // wave 0..3 -> i-tile / ph-tile
    const int l   = tid & 63;
    const int m   = l & 15;       // A/B row within tile; C col within tile
    const int q   = l >> 4;       // k-quad; C row group
    const size_t base = (size_t)blockIdx.x * NN;   // blockIdx.x = b*C + c

    // ---- phase 1: V -> VT (scalar transpose, swizzled col blocks) ----
    {
        const uint4* src = (const uint4*)(Vs + base);
        #pragma unroll
        for (int v = 0; v < 2; ++v) {
            int e = tid + 256 * v;           // 0..511, covers 8 elems each
            uint4 r = src[e];
            bf16 tmp[8]; memcpy(tmp, &r, 16);
            int pw = e >> 3;                 // V row (column of VT)
            int a  = e & 7;                  // = ph>>3 for all 8 elems
            int cs = (((pw >> 3) ^ a) & 7) << 3;  // swizzled col-block base
            int c7 = pw & 7;
            #pragma unroll
            for (int t = 0; t < 8; ++t)
                VT[(8 * a + t) * 72 + cs + c7] = tmp[t];
        }
    }

    // ---- phase 2: T = Q K^T (rows 16w..16w+15, all 64 cols) ----
    f32x4 tacc[4];
    {
        const f32x4 z = {0.f, 0.f, 0.f, 0.f};
        short8 aQ[2];
        #pragma unroll
        for (int ks = 0; ks < 2; ++ks)
            aQ[ks] = *(const short8*)(Qs + base + (16 * w + m) * 64 + q * 8 + 32 * ks);
        __builtin_amdgcn_s_setprio(1);
        #pragma unroll
        for (int tj = 0; tj < 4; ++tj) {
            tacc[tj] = z;
            #pragma unroll
            for (int ks = 0; ks < 2; ++ks) {
                short8 bK = *(const short8*)(Ks + base + (16 * tj + m) * 64 + q * 8 + 32 * ks);
                tacc[tj] = __builtin_amdgcn_mfma_f32_16x16x32_bf16(aQ[ks], bK, tacc[tj], 0, 0, 0);
            }
        }
        __builtin_amdgcn_s_setprio(0);
    }

    // ---- phase 3a: S1 = softmax over col-pooled rows (32 logits/row) ----
    {
        float p[4][4], e[4][4], mx[4], s[4];
        #pragma unroll
        for (int r = 0; r < 4; ++r) mx[r] = -1e30f;
        #pragma unroll
        for (int t = 0; t < 4; ++t)
            #pragma unroll
            for (int r = 0; r < 4; ++r) {
                float v  = tacc[t][r];
                float pv = (v + __shfl_xor(v, 1)) * (0.5f * SCALE);  // pooled pair
                p[t][r] = pv;
                mx[r]   = fmaxf(mx[r], pv);
            }
        #pragma unroll
        for (int r = 0; r < 4; ++r) {
            #pragma unroll
            for (int d = 1; d < 16; d <<= 1)
                mx[r] = fmaxf(mx[r], __shfl_xor(mx[r], d));
            s[r] = 0.f;
        }
        #pragma unroll
        for (int t = 0; t < 4; ++t)
            #pragma unroll
            for (int r = 0; r < 4; ++r) {
                e[t][r] = __expf(p[t][r] - mx[r]);
                s[r] += e[t][r];
            }
        #pragma unroll
        for (int r = 0; r < 4; ++r) {
            #pragma unroll
            for (int d = 1; d < 16; d <<= 1)
                s[r] += __shfl_xor(s[r], d);
            s[r] = 2.0f / s[r];   // each jp counted twice in the lane reduction
        }
        if (!(l & 1)) {
            int jc = m >> 1;      // pooled col within tile (0..7)
            #pragma unroll
            for (int t = 0; t < 4; ++t)
                #pragma unroll
                for (int r = 0; r < 4; ++r)
                    S1b[(16 * w + q * 4 + r) * 40 + t * 8 + jc] =
                        __float2bfloat16(e[t][r] * s[r]);
        }
    }

    // ---- phase 3b: S2 = softmax over rows of row-pooled T (64 logits/row) ----
    {
        float p2[4][2], e2[4][2], mx[2], s[2];
        #pragma unroll
        for (int h = 0; h < 2; ++h) mx[h] = -1e30f;
        #pragma unroll
        for (int t = 0; t < 4; ++t)
            #pragma unroll
            for (int h = 0; h < 2; ++h) {
                float pv = (tacc[t][2 * h] + tacc[t][2 * h + 1]) * (0.5f * SCALE);
                p2[t][h] = pv;
                mx[h]    = fmaxf(mx[h], pv);
            }
        #pragma unroll
        for (int h = 0; h < 2; ++h) {
            #pragma unroll
            for (int d = 1; d < 16; d <<= 1)
                mx[h] = fmaxf(mx[h], __shfl_xor(mx[h], d));
            s[h] = 0.f;
        }
        #pragma unroll
        for (int t = 0; t < 4; ++t)
            #pragma unroll
            for (int h = 0; h < 2; ++h) {
                e2[t][h] = __expf(p2[t][h] - mx[h]);
                s[h] += e2[t][h];
            }
        #pragma unroll
        for (int h = 0; h < 2; ++h) {
            #pragma unroll
            for (int d = 1; d < 16; d <<= 1)
                s[h] += __shfl_xor(s[h], d);
            s[h] = 1.0f / s[h];
        }
        #pragma unroll
        for (int t = 0; t < 4; ++t)
            #pragma unroll
            for (int h = 0; h < 2; ++h)
                S2b[(8 * w + q * 2 + h) * 72 + t * 16 + m] =
                    __float2bfloat16(e2[t][h] * s[h]);
    }
    __syncthreads();   // VT, S1b, S2b now visible to all waves

    // ---- phase 4: KVT[ph][ip] = sum_j VT[ph][j] * S2[ip][j] ----
    {
        const int rb = (2 * w + (m >> 3)) & 7;   // ph>>3 for row 16w+m
        short8 aV[2];
        #pragma unroll
        for (int ks = 0; ks < 2; ++ks)
            aV[ks] = *(const short8*)&VT[(16 * w + m) * 72 +
                                         (((q + 4 * ks) ^ rb) & 7) * 8];
        __builtin_amdgcn_s_setprio(1);
        #pragma unroll
        for (int tn = 0; tn < 2; ++tn) {
            f32x4 kacc = {0.f, 0.f, 0.f, 0.f};
            #pragma unroll
            for (int ks = 0; ks < 2; ++ks) {
                short8 bS = *(const short8*)&S2b[(16 * tn + m) * 72 + q * 8 + 32 * ks];
                kacc = __builtin_amdgcn_mfma_f32_16x16x32_bf16(aV[ks], bS, kacc, 0, 0, 0);
            }
            #pragma unroll
            for (int r = 0; r < 4; ++r)
                KVT[(16 * w + q * 4 + r) * 40 + 16 * tn + m] = __float2bfloat16(kacc[r]);
        }
        __builtin_amdgcn_s_setprio(0);
    }
    __syncthreads();   // KVT visible; all VT reads complete

    // ---- phase 5: out[i][ph] = sum_jp S1[i][jp] * KVT[ph][jp] ----
    f32x4 oacc[4];
    {
        short8 aS = *(const short8*)&S1b[(16 * w + m) * 40 + q * 8];
        __builtin_amdgcn_s_setprio(1);
        #pragma unroll
        for (int tn = 0; tn < 4; ++tn) {
            short8 bKV = *(const short8*)&KVT[(16 * tn + m) * 40 + q * 8];
            f32x4 z = {0.f, 0.f, 0.f, 0.f};
            oacc[tn] = __builtin_amdgcn_mfma_f32_16x16x32_bf16(aS, bKV, z, 0, 0, 0);
        }
        __builtin_amdgcn_s_setprio(0);
    }

    // ---- phase 6: stage out (bf16) into VT region, then coalesced store ----
    {
        bf16* OutS = VT;   // [64][72], VT dead (all reads before last barrier)
        #pragma unroll
        for (int tn = 0; tn < 4; ++tn)
            #pragma unroll
            for (int r = 0; r < 4; ++r)
                OutS[(16 * w + q * 4 + r) * 72 + 16 * tn + m] = __float2bfloat16(oacc[tn][r]);
        __syncthreads();
        uint* Og = (uint*)(Os + base);
        #pragma unroll
        for (int v = 0; v < 8; ++v) {
            int e  = tid + 256 * v;    // 0..2047
            int i  = e >> 5;
            int pp = e & 31;
            Og[e] = *(uint*)&OutS[i * 72 + 2 * pp];
        }
    }
}

// ---------------------------------------------------------------------------
// Kernel 3: spatial [B,C,N] (bf16) -> [B,N,C] (f32) tiled transpose.
// ---------------------------------------------------------------------------
__global__ __launch_bounds__(256) void unspat_kernel(
    const bf16* __restrict__ Os, float* __restrict__ out)
{
    __shared__ float t[32][65];
    const int b  = blockIdx.z;
    const int c0 = blockIdx.y * 32;
    const int n0 = blockIdx.x * 64;
    const int tx = threadIdx.x & 31;
    const int ty = threadIdx.x >> 5;
    const bf162* src = (const bf162*)(Os + ((size_t)b * NC + c0) * NN + n0);
    #pragma unroll
    for (int r = 0; r < 4; ++r) {
        int cc = ty + r * 8;
        float2 f = __bfloat1622float2(src[(size_t)cc * (NN/2) + tx]);
        t[cc][2*tx] = f.x; t[cc][2*tx+1] = f.y;
    }
    __syncthreads();
    float* dst = out + ((size_t)b * NN + n0) * NC + c0;
    #pragma unroll
    for (int r = 0; r < 8; ++r) {
        int nn = ty + r * 8;
        dst[(size_t)nn * NC + tx] = t[tx][nn];
    }
}

// ---------------------------------------------------------------------------
extern "C" void kernel_launch(void* const* d_in, const int* in_sizes, int n_in,
                              void* d_out, int out_size, void* d_ws, size_t ws_size,
                              hipStream_t stream)
{
    const float* x  = (const float*)d_in[0];
    const float* Wq = (const float*)d_in[1];
    const float* bq = (const float*)d_in[2];
    const float* Wk = (const float*)d_in[3];
    const float* bk = (const float*)d_in[4];
    const float* Wv = (const float*)d_in[5];
    const float* bv = (const float*)d_in[6];
    float* out = (float*)d_out;

    const size_t S = (size_t)NB * NC * NN;   // 33,554,432 elems per tensor
    bf16* Qb = (bf16*)d_ws;                  // ws >= 3*S*2 = 201,326,592 B
    bf16* Kb = Qb + S;
    bf16* Vb = Kb + S;
    bf16* xb = (bf16*)d_out;                 // dead until unspat overwrites
    bf16* Wb = ((bf16*)d_out) + S;           // 1.5 MB, in d_out spare space

    cast_x_kernel<<<dim3((NB * NN * NC) / (256 * 8)), 256, 0, stream>>>(x, xb);
    cast_w_kernel<<<dim3((NC * NC) / (256 * 8), 3), 256, 0, stream>>>(Wq, Wk, Wv, Wb);
    proj_mfma<<<dim3(12, (NB * NN) / 128), 256, 0, stream>>>(
        xb, Wb, bq, bk, bv, Qb, Kb, Vb);
    // attention writes its output into the Q region (each block's slice is
    // disjoint and its Q reads complete before its writes).
    attn_mfma<<<dim3(NB * NC), 256, 0, stream>>>(Qb, Kb, Vb, Qb);
    unspat_kernel<<<dim3(NN / 64, NC / 32, NB), 256, 0, stream>>>(Qb, out);
}